// Round 6
// baseline (308.777 us; speedup 1.0000x reference)
//
#include <hip/hip_runtime.h>

typedef __bf16 bf16x8 __attribute__((ext_vector_type(8)));
typedef float f32x16 __attribute__((ext_vector_type(16)));

// ---------------------------------------------------------------------------
// Pack W (512x512 f32, row-major W[k][n]) into bf16 MFMA-fragment order:
//   P[((c*32 + kb)*64 + l)*8 + e] = W[kb*16 + (l>>5)*8 + e][c*32 + (l&31)]
// so a wave's B-fragment load for (col-block c, k-block kb) is ONE contiguous
// 1 KB global_load_dwordx4 at P + ((c*32+kb)*64 + lane)*16 bytes.
// ---------------------------------------------------------------------------
__global__ __launch_bounds__(256) void prep_pack(const float* __restrict__ Wcb,
                                                 const float* __restrict__ Wcc,
                                                 __bf16* __restrict__ Pb,
                                                 __bf16* __restrict__ Pc) {
  int idx = blockIdx.x * 256 + threadIdx.x;          // 0 .. 524287
  const float* src = (idx < 262144) ? Wcb : Wcc;
  __bf16* dst = (idx < 262144) ? Pb : Pc;
  int t = idx & 262143;
  int e = t & 7, l = (t >> 3) & 63, kb = (t >> 9) & 31, c = t >> 14;
  int k = kb * 16 + ((l >> 5) << 3) + e;
  int n = (c << 5) + (l & 31);
  dst[t] = (__bf16)src[k * 512 + n];                 // stores coalesced
}

// ---------------------------------------------------------------------------
// Small fp32 GEMM for the node MLP: C[1024,N] = act(A[1024,K] @ W[K,N] + bias)
// ---------------------------------------------------------------------------
__global__ __launch_bounds__(256) void gemm_f32(const float* __restrict__ A,
                                                const float* __restrict__ W,
                                                const float* __restrict__ bias,
                                                float* __restrict__ C,
                                                int K, int N, int do_relu) {
  __shared__ float As[16][68];
  __shared__ float Ws[16][32];
  int bm = blockIdx.x * 64, bn = blockIdx.y * 32;
  int tid = threadIdx.x;
  int tx = tid & 15, ty = tid >> 4;
  float acc[4][2] = {};
  for (int k0 = 0; k0 < K; k0 += 16) {
#pragma unroll
    for (int ii = 0; ii < 4; ii++) {
      int e = ii * 256 + tid; int r = e >> 4, c = e & 15;
      As[c][r] = A[(bm + r) * K + k0 + c];
    }
#pragma unroll
    for (int ii = 0; ii < 2; ii++) {
      int e = ii * 256 + tid; int kr = e >> 5, c = e & 31;
      Ws[kr][c] = W[(k0 + kr) * N + bn + c];
    }
    __syncthreads();
#pragma unroll
    for (int kk = 0; kk < 16; kk++) {
      float4 a = *(const float4*)&As[kk][ty * 4];
      float2 w = *(const float2*)&Ws[kk][tx * 2];
      acc[0][0] += a.x * w.x; acc[0][1] += a.x * w.y;
      acc[1][0] += a.y * w.x; acc[1][1] += a.y * w.y;
      acc[2][0] += a.z * w.x; acc[2][1] += a.z * w.y;
      acc[3][0] += a.w * w.x; acc[3][1] += a.w * w.y;
    }
    __syncthreads();
  }
#pragma unroll
  for (int mi = 0; mi < 4; mi++)
#pragma unroll
    for (int ni = 0; ni < 2; ni++) {
      int n = bn + tx * 2 + ni;
      float vv = acc[mi][ni] + (bias ? bias[n] : 0.f);
      if (do_relu) vv = fmaxf(vv, 0.f);
      C[(bm + ty * 4 + mi) * N + n] = vv;
    }
}

// ---------------------------------------------------------------------------
// Fused edge kernel. One WG = (b, i, ALL 128 j) as two 64-row tiles in
// 128 KB LDS — 1024 threads = 16 waves. Waves 0-7 process tile 0, waves
// 8-15 process tile 1; per-wave code is verbatim the round-3 passing
// single-tile kernel (acc[4], 4 MFMAs/kb) with a tile base offset.
// 4 waves/SIMD latency hiding + paired waves across tile groups read
// identical B streams (L1 reuse).
// LDS tile t at t*65536: byte = row*1024 + ((col*2)^((row&15)<<4))
// Within a tile group: wave wi -> rows (wi&1)*32..+32, cols (wi>>1)*128..+128
// ---------------------------------------------------------------------------
__global__ __launch_bounds__(1024, 4) void edge_kernel(
    const float* __restrict__ u, const float* __restrict__ v,
    const bf16x8* __restrict__ Pb, const bf16x8* __restrict__ Pc,
    const float* __restrict__ bca, const float* __restrict__ bcb,
    const float* __restrict__ bcc, const float* __restrict__ Wo,
    const float* __restrict__ bo, float* __restrict__ out) {
  __shared__ __align__(16) char h_raw[131072];

  int wg = blockIdx.x;                 // b*128 + i
  int i = wg & 127, b = wg >> 7;
  int tid = threadIdx.x, lane = tid & 63, w = tid >> 6;

  // ---- phase 1: h1 = relu(u[j] + v[i] + bca) for j = 0..127 ----
  {
    int k2 = tid & 255;                                    // fixed col-pair
    float2 vv = *(const float2*)(v + (b * 128 + i) * 512 + 2 * k2);
    float2 bc = *(const float2*)(bca + 2 * k2);
    float vb0 = vv.x + bc.x, vb1 = vv.y + bc.y;
    const float* ub = u + (b * 128) * 512;
#pragma unroll 4
    for (int it = 0; it < 32; it++) {
      int r = it * 4 + (tid >> 8);                         // 0..127
      float2 uu = *(const float2*)(ub + r * 512 + 2 * k2);
      float x0 = fmaxf(uu.x + vb0, 0.f);
      float x1 = fmaxf(uu.y + vb1, 0.f);
      unsigned short s0 = __builtin_bit_cast(unsigned short, (__bf16)x0);
      unsigned short s1 = __builtin_bit_cast(unsigned short, (__bf16)x1);
      unsigned int pk = ((unsigned int)s1 << 16) | (unsigned int)s0;
      int rt = r & 63;
      int wbyte = ((r >> 6) << 16) + rt * 1024 + ((4 * k2) ^ ((rt & 15) << 4));
      *(unsigned int*)(h_raw + wbyte) = pk;
    }
  }
  __syncthreads();

  int tg = w >> 3;                     // tile group (0 or 1)
  int wi = w & 7;                      // wave within group (round-3 'w')
  int tbase = tg << 16;                // tile LDS base
  int mrow = (wi & 1) * 32;
  int n0 = (wi >> 1) * 128;
  int cg4 = (wi >> 1) * 4;             // first col-block of this wave's strip
  int arow = mrow + (lane & 31);
  int sA = (arow & 15) << 4;
  int klo = (lane >> 5) * 8;

  // packed B fragment pointers (bf16x8 units); frag idx = (c*32+kb)*64 + lane
  const bf16x8* Bb0 = Pb + ((cg4 + 0) * 32) * 64 + lane;
  const bf16x8* Bb1 = Pb + ((cg4 + 1) * 32) * 64 + lane;
  const bf16x8* Bb2 = Pb + ((cg4 + 2) * 32) * 64 + lane;
  const bf16x8* Bb3 = Pb + ((cg4 + 3) * 32) * 64 + lane;
  const bf16x8* Bc0 = Pc + ((cg4 + 0) * 32) * 64 + lane;
  const bf16x8* Bc1 = Pc + ((cg4 + 1) * 32) * 64 + lane;
  const bf16x8* Bc2 = Pc + ((cg4 + 2) * 32) * 64 + lane;
  const bf16x8* Bc3 = Pc + ((cg4 + 3) * 32) * 64 + lane;

  f32x16 acc[4];

  // ---- GEMM 1: h2 = h1 @ Wcb ----
#pragma unroll
  for (int nb = 0; nb < 4; nb++)
#pragma unroll
    for (int r = 0; r < 16; r++) acc[nb][r] = 0.f;
#pragma unroll 2
  for (int kb = 0; kb < 32; kb++) {
    int abyte = tbase + arow * 1024 + (((kb * 16 + klo) * 2) ^ sA);
    bf16x8 a = *(const bf16x8*)(h_raw + abyte);
    bf16x8 b0 = Bb0[kb * 64];
    bf16x8 b1 = Bb1[kb * 64];
    bf16x8 b2 = Bb2[kb * 64];
    bf16x8 b3 = Bb3[kb * 64];
    acc[0] = __builtin_amdgcn_mfma_f32_32x32x16_bf16(a, b0, acc[0], 0, 0, 0);
    acc[1] = __builtin_amdgcn_mfma_f32_32x32x16_bf16(a, b1, acc[1], 0, 0, 0);
    acc[2] = __builtin_amdgcn_mfma_f32_32x32x16_bf16(a, b2, acc[2], 0, 0, 0);
    acc[3] = __builtin_amdgcn_mfma_f32_32x32x16_bf16(a, b3, acc[3], 0, 0, 0);
  }
  __syncthreads();   // all h1 reads done before overwrite

  // ---- epilogue 1: h2 = relu(acc + bcb) -> bf16 LDS (swizzled) ----
#pragma unroll
  for (int nb = 0; nb < 4; nb++) {
    int cn = n0 + nb * 32 + (lane & 31);
    float bbv = bcb[cn];
#pragma unroll
    for (int r = 0; r < 16; r++) {
      int row = mrow + (r & 3) + 8 * (r >> 2) + 4 * (lane >> 5);
      float val = fmaxf(acc[nb][r] + bbv, 0.f);
      int byte_ = tbase + row * 1024 + ((cn * 2) ^ ((row & 15) << 4));
      *(__bf16*)(h_raw + byte_) = (__bf16)val;
    }
  }
  __syncthreads();

  // ---- GEMM 2: h3 = h2 @ Wcc ----
#pragma unroll
  for (int nb = 0; nb < 4; nb++)
#pragma unroll
    for (int r = 0; r < 16; r++) acc[nb][r] = 0.f;
#pragma unroll 2
  for (int kb = 0; kb < 32; kb++) {
    int abyte = tbase + arow * 1024 + (((kb * 16 + klo) * 2) ^ sA);
    bf16x8 a = *(const bf16x8*)(h_raw + abyte);
    bf16x8 b0 = Bc0[kb * 64];
    bf16x8 b1 = Bc1[kb * 64];
    bf16x8 b2 = Bc2[kb * 64];
    bf16x8 b3 = Bc3[kb * 64];
    acc[0] = __builtin_amdgcn_mfma_f32_32x32x16_bf16(a, b0, acc[0], 0, 0, 0);
    acc[1] = __builtin_amdgcn_mfma_f32_32x32x16_bf16(a, b1, acc[1], 0, 0, 0);
    acc[2] = __builtin_amdgcn_mfma_f32_32x32x16_bf16(a, b2, acc[2], 0, 0, 0);
    acc[3] = __builtin_amdgcn_mfma_f32_32x32x16_bf16(a, b3, acc[3], 0, 0, 0);
  }

  // ---- epilogue 2: h3 = relu(acc + bcc); out partials = h3 @ Wo (fp32) ----
  float p[16][2] = {};
#pragma unroll
  for (int nb = 0; nb < 4; nb++) {
    int cn = n0 + nb * 32 + (lane & 31);
    float bcv = bcc[cn];
    float2 wov = *(const float2*)(Wo + cn * 2);
#pragma unroll
    for (int r = 0; r < 16; r++) {
      float h3 = fmaxf(acc[nb][r] + bcv, 0.f);
      p[r][0] += h3 * wov.x;
      p[r][1] += h3 * wov.y;
    }
  }
  // reduce over the 32 col-lanes (rows differ across the two 32-lane halves)
#pragma unroll
  for (int m = 1; m <= 16; m <<= 1) {
#pragma unroll
    for (int r = 0; r < 16; r++) {
      p[r][0] += __shfl_xor(p[r][0], m, 64);
      p[r][1] += __shfl_xor(p[r][1], m, 64);
    }
  }
  __syncthreads();                 // all GEMM2 LDS reads done; reuse h_raw
  float* red = (float*)h_raw;      // [2 tiles][4 colgroups][64 rows][2] = 4 KB
  if ((lane & 31) == 0) {
    int hh = lane >> 5, cg = wi >> 1;
#pragma unroll
    for (int r = 0; r < 16; r++) {
      int row = mrow + (r & 3) + 8 * (r >> 2) + 4 * hh;
      red[((tg * 4 + cg) * 64 + row) * 2 + 0] = p[r][0];
      red[((tg * 4 + cg) * 64 + row) * 2 + 1] = p[r][1];
    }
  }
  __syncthreads();
  if (tid < 256) {
    int row = tid >> 1, d = tid & 1;   // row = j in 0..127
    int rt = row >> 6, rr = row & 63;
    float s = red[((rt * 4 + 0) * 64 + rr) * 2 + d] +
              red[((rt * 4 + 1) * 64 + rr) * 2 + d] +
              red[((rt * 4 + 2) * 64 + rr) * 2 + d] +
              red[((rt * 4 + 3) * 64 + rr) * 2 + d] + bo[d];
    out[((b * 128 + i) * 128 + row) * 2 + d] = s;
  }
}

// ---------------------------------------------------------------------------
extern "C" void kernel_launch(void* const* d_in, const int* in_sizes, int n_in,
                              void* d_out, int out_size, void* d_ws, size_t ws_size,
                              hipStream_t stream) {
  const float* x   = (const float*)d_in[0];
  const float* Wa  = (const float*)d_in[1];
  const float* ba  = (const float*)d_in[2];
  const float* Wb  = (const float*)d_in[3];
  const float* bb  = (const float*)d_in[4];
  const float* Wca = (const float*)d_in[5];
  const float* bca = (const float*)d_in[6];
  const float* Wcb = (const float*)d_in[7];
  const float* bcb = (const float*)d_in[8];
  const float* Wcc = (const float*)d_in[9];
  const float* bcc = (const float*)d_in[10];
  const float* Wo  = (const float*)d_in[11];
  const float* bo  = (const float*)d_in[12];
  float* out = (float*)d_out;

  char* ws = (char*)d_ws;
  float* f1 = (float*)(ws);                          // 2 MB
  float* f  = (float*)(ws + (2u << 20));             // 2 MB
  float* u  = (float*)(ws + (4u << 20));             // 2 MB
  float* v  = (float*)(ws + (6u << 20));             // 2 MB
  __bf16* Pb = (__bf16*)(ws + (8u << 20));           // 512 KB packed Wcb
  __bf16* Pc = (__bf16*)(ws + (8u << 20) + (512u << 10));  // 512 KB packed Wcc

  prep_pack<<<2048, 256, 0, stream>>>(Wcb, Wcc, Pb, Pc);
  gemm_f32<<<dim3(16, 16), 256, 0, stream>>>(x, Wa, ba, f1, 256, 512, 1);
  gemm_f32<<<dim3(16, 16), 256, 0, stream>>>(f1, Wb, bb, f, 512, 512, 1);
  gemm_f32<<<dim3(16, 16), 256, 0, stream>>>(f, Wca, nullptr, u, 512, 512, 0);
  gemm_f32<<<dim3(16, 16), 256, 0, stream>>>(f, Wca + 512 * 512, nullptr, v, 512, 512, 0);
  edge_kernel<<<1024, 1024, 0, stream>>>(u, v, (const bf16x8*)Pb, (const bf16x8*)Pc,
                                         bca, bcb, bcc, Wo, bo, out);
}

// Round 7
// 255.556 us; speedup vs baseline: 1.2083x; 1.2083x over previous
//
#include <hip/hip_runtime.h>

typedef __bf16 bf16x8 __attribute__((ext_vector_type(8)));
typedef float f32x16 __attribute__((ext_vector_type(16)));

// ---------------------------------------------------------------------------
// Pack W (512x512 f32, row-major W[k][n]) into bf16 MFMA-fragment order:
//   P[((c*32 + kb)*64 + l)*8 + e] = W[kb*16 + (l>>5)*8 + e][c*32 + (l&31)]
// so a wave's B-fragment load for (col-block c, k-block kb) is ONE contiguous
// 1 KB global_load_dwordx4 at P + ((c*32+kb)*64 + lane)*16 bytes.
// ---------------------------------------------------------------------------
__global__ __launch_bounds__(256) void prep_pack(const float* __restrict__ Wcb,
                                                 const float* __restrict__ Wcc,
                                                 __bf16* __restrict__ Pb,
                                                 __bf16* __restrict__ Pc) {
  int idx = blockIdx.x * 256 + threadIdx.x;          // 0 .. 524287
  const float* src = (idx < 262144) ? Wcb : Wcc;
  __bf16* dst = (idx < 262144) ? Pb : Pc;
  int t = idx & 262143;
  int e = t & 7, l = (t >> 3) & 63, kb = (t >> 9) & 31, c = t >> 14;
  int k = kb * 16 + ((l >> 5) << 3) + e;
  int n = (c << 5) + (l & 31);
  dst[t] = (__bf16)src[k * 512 + n];                 // stores coalesced
}

// ---------------------------------------------------------------------------
// Small fp32 GEMM for the node MLP: C[1024,N] = act(A[1024,K] @ W[K,N] + bias)
// ---------------------------------------------------------------------------
__global__ __launch_bounds__(256) void gemm_f32(const float* __restrict__ A,
                                                const float* __restrict__ W,
                                                const float* __restrict__ bias,
                                                float* __restrict__ C,
                                                int K, int N, int do_relu) {
  __shared__ float As[16][68];
  __shared__ float Ws[16][32];
  int bm = blockIdx.x * 64, bn = blockIdx.y * 32;
  int tid = threadIdx.x;
  int tx = tid & 15, ty = tid >> 4;
  float acc[4][2] = {};
  for (int k0 = 0; k0 < K; k0 += 16) {
#pragma unroll
    for (int ii = 0; ii < 4; ii++) {
      int e = ii * 256 + tid; int r = e >> 4, c = e & 15;
      As[c][r] = A[(bm + r) * K + k0 + c];
    }
#pragma unroll
    for (int ii = 0; ii < 2; ii++) {
      int e = ii * 256 + tid; int kr = e >> 5, c = e & 31;
      Ws[kr][c] = W[(k0 + kr) * N + bn + c];
    }
    __syncthreads();
#pragma unroll
    for (int kk = 0; kk < 16; kk++) {
      float4 a = *(const float4*)&As[kk][ty * 4];
      float2 w = *(const float2*)&Ws[kk][tx * 2];
      acc[0][0] += a.x * w.x; acc[0][1] += a.x * w.y;
      acc[1][0] += a.y * w.x; acc[1][1] += a.y * w.y;
      acc[2][0] += a.z * w.x; acc[2][1] += a.z * w.y;
      acc[3][0] += a.w * w.x; acc[3][1] += a.w * w.y;
    }
    __syncthreads();
  }
#pragma unroll
  for (int mi = 0; mi < 4; mi++)
#pragma unroll
    for (int ni = 0; ni < 2; ni++) {
      int n = bn + tx * 2 + ni;
      float vv = acc[mi][ni] + (bias ? bias[n] : 0.f);
      if (do_relu) vv = fmaxf(vv, 0.f);
      C[(bm + ty * 4 + mi) * N + n] = vv;
    }
}

// ---------------------------------------------------------------------------
// Fused u/v kernel: u = f @ Wca[0:512,:], v = f @ Wca[512:1024,:] — same body
// as gemm_f32 (K=512, N=512, no bias/relu), one launch, grid (16, 32).
// ---------------------------------------------------------------------------
__global__ __launch_bounds__(256) void gemm_uv(const float* __restrict__ A,
                                               const float* __restrict__ Wca,
                                               float* __restrict__ u,
                                               float* __restrict__ v) {
  __shared__ float As[16][68];
  __shared__ float Ws[16][32];
  int half = blockIdx.y >> 4;
  const float* W = Wca + half * 512 * 512;
  float* C = half ? v : u;
  int bm = blockIdx.x * 64, bn = (blockIdx.y & 15) * 32;
  int tid = threadIdx.x;
  int tx = tid & 15, ty = tid >> 4;
  float acc[4][2] = {};
  for (int k0 = 0; k0 < 512; k0 += 16) {
#pragma unroll
    for (int ii = 0; ii < 4; ii++) {
      int e = ii * 256 + tid; int r = e >> 4, c = e & 15;
      As[c][r] = A[(bm + r) * 512 + k0 + c];
    }
#pragma unroll
    for (int ii = 0; ii < 2; ii++) {
      int e = ii * 256 + tid; int kr = e >> 5, c = e & 31;
      Ws[kr][c] = W[(k0 + kr) * 512 + bn + c];
    }
    __syncthreads();
#pragma unroll
    for (int kk = 0; kk < 16; kk++) {
      float4 a = *(const float4*)&As[kk][ty * 4];
      float2 w = *(const float2*)&Ws[kk][tx * 2];
      acc[0][0] += a.x * w.x; acc[0][1] += a.x * w.y;
      acc[1][0] += a.y * w.x; acc[1][1] += a.y * w.y;
      acc[2][0] += a.z * w.x; acc[2][1] += a.z * w.y;
      acc[3][0] += a.w * w.x; acc[3][1] += a.w * w.y;
    }
    __syncthreads();
  }
#pragma unroll
  for (int mi = 0; mi < 4; mi++)
#pragma unroll
    for (int ni = 0; ni < 2; ni++)
      C[(bm + ty * 4 + mi) * 512 + bn + tx * 2 + ni] = acc[mi][ni];
}

// ---------------------------------------------------------------------------
// Fused edge kernel, two-tile B-sharing (round-5 passing dataflow, verbatim).
// Round-7 delta: explicit depth-2 ping-pong prefetch of the 4 B fragments —
// MFMAs at step kb consume registers loaded at kb-1; loads for kb+1 issue
// before the A ds_reads. Initial B loads hoisted before the preceding
// barriers. Consumed values identical -> bit-identical output.
// One WG = (b, i, ALL 128 j) as two 64-row tiles in 128 KB LDS.
// LDS tile t at t*65536: byte = row*1024 + ((col*2)^((row&15)<<4))
// 8 waves: wave w -> rows (w&1)*32..+32 (per tile), cols (w>>1)*128..+128
// ---------------------------------------------------------------------------
__global__ __launch_bounds__(512, 2) void edge_kernel(
    const float* __restrict__ u, const float* __restrict__ v,
    const bf16x8* __restrict__ Pb, const bf16x8* __restrict__ Pc,
    const float* __restrict__ bca, const float* __restrict__ bcb,
    const float* __restrict__ bcc, const float* __restrict__ Wo,
    const float* __restrict__ bo, float* __restrict__ out) {
  __shared__ __align__(16) char h_raw[131072];

  int wg = blockIdx.x;                 // b*128 + i
  int i = wg & 127, b = wg >> 7;
  int tid = threadIdx.x, lane = tid & 63, w = tid >> 6;

  int mrow = (w & 1) * 32;
  int n0 = (w >> 1) * 128;
  int cg4 = (w >> 1) * 4;              // first col-block of this wave's strip
  int arow = mrow + (lane & 31);
  int sA = (arow & 15) << 4;
  int klo = (lane >> 5) * 8;

  // packed B fragment pointers (bf16x8 units); frag idx = (c*32+kb)*64 + lane
  const bf16x8* Bb0 = Pb + ((cg4 + 0) * 32) * 64 + lane;
  const bf16x8* Bb1 = Pb + ((cg4 + 1) * 32) * 64 + lane;
  const bf16x8* Bb2 = Pb + ((cg4 + 2) * 32) * 64 + lane;
  const bf16x8* Bb3 = Pb + ((cg4 + 3) * 32) * 64 + lane;
  const bf16x8* Bc0 = Pc + ((cg4 + 0) * 32) * 64 + lane;
  const bf16x8* Bc1 = Pc + ((cg4 + 1) * 32) * 64 + lane;
  const bf16x8* Bc2 = Pc + ((cg4 + 2) * 32) * 64 + lane;
  const bf16x8* Bc3 = Pc + ((cg4 + 3) * 32) * 64 + lane;

  // issue GEMM1's first B loads NOW — in flight during phase 1
  bf16x8 pf0 = Bb0[0], pf1 = Bb1[0], pf2 = Bb2[0], pf3 = Bb3[0];

  // ---- phase 1: h1 = relu(u[j] + v[i] + bca) for j = 0..127 ----
  {
    int k2 = tid & 255;                                    // fixed col-pair
    float2 vv = *(const float2*)(v + (b * 128 + i) * 512 + 2 * k2);
    float2 bc = *(const float2*)(bca + 2 * k2);
    float vb0 = vv.x + bc.x, vb1 = vv.y + bc.y;
    const float* ub = u + (b * 128) * 512;
#pragma unroll 4
    for (int it = 0; it < 64; it++) {
      int r = it * 2 + (tid >> 8);                         // 0..127
      float2 uu = *(const float2*)(ub + r * 512 + 2 * k2);
      float x0 = fmaxf(uu.x + vb0, 0.f);
      float x1 = fmaxf(uu.y + vb1, 0.f);
      unsigned short s0 = __builtin_bit_cast(unsigned short, (__bf16)x0);
      unsigned short s1 = __builtin_bit_cast(unsigned short, (__bf16)x1);
      unsigned int pk = ((unsigned int)s1 << 16) | (unsigned int)s0;
      int rt = r & 63;
      int wbyte = ((r >> 6) << 16) + rt * 1024 + ((4 * k2) ^ ((rt & 15) << 4));
      *(unsigned int*)(h_raw + wbyte) = pk;
    }
  }
  __syncthreads();

  f32x16 acc0[4], acc1[4];             // tile 0 / tile 1

  // ---- GEMM 1: h2 = h1 @ Wcb (both tiles share B; depth-2 B ping-pong) ----
#pragma unroll
  for (int nb = 0; nb < 4; nb++)
#pragma unroll
    for (int r = 0; r < 16; r++) { acc0[nb][r] = 0.f; acc1[nb][r] = 0.f; }
#pragma unroll 2
  for (int kb = 0; kb < 32; kb++) {
    bf16x8 b0 = pf0, b1 = pf1, b2 = pf2, b3 = pf3;
    if (kb < 31) {
      pf0 = Bb0[(kb + 1) * 64];
      pf1 = Bb1[(kb + 1) * 64];
      pf2 = Bb2[(kb + 1) * 64];
      pf3 = Bb3[(kb + 1) * 64];
    }
    int abyte = arow * 1024 + (((kb * 16 + klo) * 2) ^ sA);
    bf16x8 a0 = *(const bf16x8*)(h_raw + abyte);
    bf16x8 a1 = *(const bf16x8*)(h_raw + 65536 + abyte);
    acc0[0] = __builtin_amdgcn_mfma_f32_32x32x16_bf16(a0, b0, acc0[0], 0, 0, 0);
    acc1[0] = __builtin_amdgcn_mfma_f32_32x32x16_bf16(a1, b0, acc1[0], 0, 0, 0);
    acc0[1] = __builtin_amdgcn_mfma_f32_32x32x16_bf16(a0, b1, acc0[1], 0, 0, 0);
    acc1[1] = __builtin_amdgcn_mfma_f32_32x32x16_bf16(a1, b1, acc1[1], 0, 0, 0);
    acc0[2] = __builtin_amdgcn_mfma_f32_32x32x16_bf16(a0, b2, acc0[2], 0, 0, 0);
    acc1[2] = __builtin_amdgcn_mfma_f32_32x32x16_bf16(a1, b2, acc1[2], 0, 0, 0);
    acc0[3] = __builtin_amdgcn_mfma_f32_32x32x16_bf16(a0, b3, acc0[3], 0, 0, 0);
    acc1[3] = __builtin_amdgcn_mfma_f32_32x32x16_bf16(a1, b3, acc1[3], 0, 0, 0);
  }

  // issue GEMM2's first B loads NOW — in flight across epilogue 1
  pf0 = Bc0[0]; pf1 = Bc1[0]; pf2 = Bc2[0]; pf3 = Bc3[0];
  __syncthreads();   // all h1 reads done before overwrite

  // ---- epilogue 1: h2 = relu(acc + bcb) -> bf16 LDS (swizzled), both tiles ----
#pragma unroll
  for (int nb = 0; nb < 4; nb++) {
    int cn = n0 + nb * 32 + (lane & 31);
    float bbv = bcb[cn];
#pragma unroll
    for (int r = 0; r < 16; r++) {
      int row = mrow + (r & 3) + 8 * (r >> 2) + 4 * (lane >> 5);
      int byte_ = row * 1024 + ((cn * 2) ^ ((row & 15) << 4));
      *(__bf16*)(h_raw + byte_) = (__bf16)fmaxf(acc0[nb][r] + bbv, 0.f);
      *(__bf16*)(h_raw + 65536 + byte_) = (__bf16)fmaxf(acc1[nb][r] + bbv, 0.f);
    }
  }
  __syncthreads();

  // ---- GEMM 2: h3 = h2 @ Wcc (both tiles share B; depth-2 B ping-pong) ----
#pragma unroll
  for (int nb = 0; nb < 4; nb++)
#pragma unroll
    for (int r = 0; r < 16; r++) { acc0[nb][r] = 0.f; acc1[nb][r] = 0.f; }
#pragma unroll 2
  for (int kb = 0; kb < 32; kb++) {
    bf16x8 b0 = pf0, b1 = pf1, b2 = pf2, b3 = pf3;
    if (kb < 31) {
      pf0 = Bc0[(kb + 1) * 64];
      pf1 = Bc1[(kb + 1) * 64];
      pf2 = Bc2[(kb + 1) * 64];
      pf3 = Bc3[(kb + 1) * 64];
    }
    int abyte = arow * 1024 + (((kb * 16 + klo) * 2) ^ sA);
    bf16x8 a0 = *(const bf16x8*)(h_raw + abyte);
    bf16x8 a1 = *(const bf16x8*)(h_raw + 65536 + abyte);
    acc0[0] = __builtin_amdgcn_mfma_f32_32x32x16_bf16(a0, b0, acc0[0], 0, 0, 0);
    acc1[0] = __builtin_amdgcn_mfma_f32_32x32x16_bf16(a1, b0, acc1[0], 0, 0, 0);
    acc0[1] = __builtin_amdgcn_mfma_f32_32x32x16_bf16(a0, b1, acc0[1], 0, 0, 0);
    acc1[1] = __builtin_amdgcn_mfma_f32_32x32x16_bf16(a1, b1, acc1[1], 0, 0, 0);
    acc0[2] = __builtin_amdgcn_mfma_f32_32x32x16_bf16(a0, b2, acc0[2], 0, 0, 0);
    acc1[2] = __builtin_amdgcn_mfma_f32_32x32x16_bf16(a1, b2, acc1[2], 0, 0, 0);
    acc0[3] = __builtin_amdgcn_mfma_f32_32x32x16_bf16(a0, b3, acc0[3], 0, 0, 0);
    acc1[3] = __builtin_amdgcn_mfma_f32_32x32x16_bf16(a1, b3, acc1[3], 0, 0, 0);
  }

  // ---- epilogue 2: h3 = relu(acc + bcc); fold Wo; shfl-reduce (fp32) ----
  float p0[16][2] = {}, p1[16][2] = {};
#pragma unroll
  for (int nb = 0; nb < 4; nb++) {
    int cn = n0 + nb * 32 + (lane & 31);
    float bcv = bcc[cn];
    float2 wov = *(const float2*)(Wo + cn * 2);
#pragma unroll
    for (int r = 0; r < 16; r++) {
      float h30 = fmaxf(acc0[nb][r] + bcv, 0.f);
      float h31 = fmaxf(acc1[nb][r] + bcv, 0.f);
      p0[r][0] += h30 * wov.x; p0[r][1] += h30 * wov.y;
      p1[r][0] += h31 * wov.x; p1[r][1] += h31 * wov.y;
    }
  }
#pragma unroll
  for (int m = 1; m <= 16; m <<= 1) {
#pragma unroll
    for (int r = 0; r < 16; r++) {
      p0[r][0] += __shfl_xor(p0[r][0], m, 64);
      p0[r][1] += __shfl_xor(p0[r][1], m, 64);
      p1[r][0] += __shfl_xor(p1[r][0], m, 64);
      p1[r][1] += __shfl_xor(p1[r][1], m, 64);
    }
  }
  __syncthreads();                 // all GEMM2 LDS reads done; reuse h_raw
  float* red = (float*)h_raw;      // [4 colgroups][128 rows][2] = 4 KB
  if ((lane & 31) == 0) {
    int hh = lane >> 5, cg = w >> 1;
#pragma unroll
    for (int r = 0; r < 16; r++) {
      int row = mrow + (r & 3) + 8 * (r >> 2) + 4 * hh;
      red[(cg * 128 + row) * 2 + 0] = p0[r][0];
      red[(cg * 128 + row) * 2 + 1] = p0[r][1];
      red[(cg * 128 + 64 + row) * 2 + 0] = p1[r][0];
      red[(cg * 128 + 64 + row) * 2 + 1] = p1[r][1];
    }
  }
  __syncthreads();
  if (tid < 256) {
    int row = tid >> 1, d = tid & 1;
    float s = red[(0 * 128 + row) * 2 + d] + red[(1 * 128 + row) * 2 + d] +
              red[(2 * 128 + row) * 2 + d] + red[(3 * 128 + row) * 2 + d] + bo[d];
    out[((b * 128 + i) * 128 + row) * 2 + d] = s;
  }
}

// ---------------------------------------------------------------------------
extern "C" void kernel_launch(void* const* d_in, const int* in_sizes, int n_in,
                              void* d_out, int out_size, void* d_ws, size_t ws_size,
                              hipStream_t stream) {
  const float* x   = (const float*)d_in[0];
  const float* Wa  = (const float*)d_in[1];
  const float* ba  = (const float*)d_in[2];
  const float* Wb  = (const float*)d_in[3];
  const float* bb  = (const float*)d_in[4];
  const float* Wca = (const float*)d_in[5];
  const float* bca = (const float*)d_in[6];
  const float* Wcb = (const float*)d_in[7];
  const float* bcb = (const float*)d_in[8];
  const float* Wcc = (const float*)d_in[9];
  const float* bcc = (const float*)d_in[10];
  const float* Wo  = (const float*)d_in[11];
  const float* bo  = (const float*)d_in[12];
  float* out = (float*)d_out;

  char* ws = (char*)d_ws;
  float* f1 = (float*)(ws);                          // 2 MB
  float* f  = (float*)(ws + (2u << 20));             // 2 MB
  float* u  = (float*)(ws + (4u << 20));             // 2 MB
  float* v  = (float*)(ws + (6u << 20));             // 2 MB
  __bf16* Pb = (__bf16*)(ws + (8u << 20));           // 512 KB packed Wcb
  __bf16* Pc = (__bf16*)(ws + (8u << 20) + (512u << 10));  // 512 KB packed Wcc

  prep_pack<<<2048, 256, 0, stream>>>(Wcb, Wcc, Pb, Pc);
  gemm_f32<<<dim3(16, 16), 256, 0, stream>>>(x, Wa, ba, f1, 256, 512, 1);
  gemm_f32<<<dim3(16, 16), 256, 0, stream>>>(f1, Wb, bb, f, 512, 512, 1);
  gemm_uv<<<dim3(16, 32), 256, 0, stream>>>(f, Wca, u, v);
  edge_kernel<<<1024, 512, 0, stream>>>(u, v, (const bf16x8*)Pb, (const bf16x8*)Pc,
                                        bca, bcb, bcc, Wo, bo, out);
}